// Round 1
// baseline (287.062 us; speedup 1.0000x reference)
//
#include <hip/hip_runtime.h>
#include <cstdint>
#include <cstddef>

#define B_SZ   8
#define SEQ    4096
#define HID    1024
#define NCH    16        // snn time chunks (was 8): 512 blocks -> 2 waves/SIMD
#define CHUNK  256       // SEQ / NCH
#define WARM   256       // warm-up steps; 0.9^256 contraction + spike-reset collapse => bit-exact
#define JTAP   16        // truncated SSM impulse-response taps
#define TS3    16        // out_kernel t-tile (2048 blocks, 8/CU)
#define YTS    256       // ssm_y t-tile (128 blocks)

typedef float vfloat4 __attribute__((ext_vector_type(4)));

// ws layout: u64 spk[B_SZ*16*SEQ] = 4 MB at offset 0
//            float y[B_SZ*SEQ]    = 128 KB at offset 4 MB
__device__ __forceinline__ void snn_step(float& v, float& r, float xv, bool& s) {
  // match reference rounding: separate mul + add (no FMA contraction)
  v = __fadd_rn(__fmul_rn(v, 0.9f), xv);
  s = (r <= 0.0f) && (v >= 1.0f);
  v = s ? 0.0f : v;
  r = s ? 5.0f : fmaxf(r - 1.0f, 0.0f);
}

__device__ __forceinline__ void proc32_emit(const float* xv, float& v, float& r, int lane,
                                            unsigned long long* __restrict__ sp, int t) {
  unsigned long long my = 0;
  #pragma unroll
  for (int k = 0; k < 32; ++k) {
    bool s; snn_step(v, r, xv[k], s);
    unsigned long long m = __ballot(s);
    my = ((lane & 31) == k) ? m : my;
  }
  if (lane < 32) sp[t + lane] = my;     // 256B coalesced burst per 32 steps
}

__device__ __forceinline__ void proc32_warm(const float* xv, float& v, float& r) {
  #pragma unroll
  for (int k = 0; k < 32; ++k) { bool s; snn_step(v, r, xv[k], s); }
}

// Phase 1: LIF scan, chunked in time with bit-exact warm-up restart.
// grid = (HID/256, B_SZ, NCH) = 512 blocks (2/CU), block = 256.
// Issued reads: (256 + 15*512)*8192 cols * 4B = 260 MB; warm re-reads are L3-hot.
__global__ __launch_bounds__(256) void snn_kernel(const float* __restrict__ x,
                                                  unsigned long long* __restrict__ spk) {
  const int hid  = blockIdx.x * 256 + threadIdx.x;
  const int b    = blockIdx.y;
  const int c    = blockIdx.z;
  const int lane = threadIdx.x & 63;
  const int wv   = hid >> 6;                 // global hid-wave index 0..15
  const int t0   = c * CHUNK;
  const int t1   = t0 + CHUNK;
  const int tw   = (t0 >= WARM) ? (t0 - WARM) : 0;  // len in {256, 512}, %64==0
  const float* __restrict__ xp = x + (size_t)(b * SEQ) * HID + hid;
  unsigned long long* __restrict__ sp = spk + (size_t)(b * 16 + wv) * SEQ;

  float v = 0.0f, r = 0.0f;
  float xa[32], xb[32];

  #pragma unroll
  for (int k = 0; k < 32; ++k) xa[k] = xp[(size_t)(tw + k) * HID];

  for (int t = tw; t < t1; t += 64) {
    // prefetch batch B while processing A
    #pragma unroll
    for (int k = 0; k < 32; ++k) xb[k] = xp[(size_t)(t + 32 + k) * HID];

    if (t >= t0) proc32_emit(xa, v, r, lane, sp, t);
    else         proc32_warm(xa, v, r);

    // prefetch next batch A while processing B
    if (t + 64 < t1) {
      #pragma unroll
      for (int k = 0; k < 32; ++k) xa[k] = xp[(size_t)(t + 64 + k) * HID];
    }

    if (t + 32 >= t0) proc32_emit(xb, v, r, lane, sp, t + 32);
    else              proc32_warm(xb, v, r);
  }
}

// Phase 2: taps (Krylov, wave0) + popcount u + 16-tap conv -> y[b][t] (128 KB).
// grid = (SEQ/YTS, B_SZ) = 128 blocks. Tiny; u math is integer (order-free, exact),
// tap + conv chains are verbatim from the previous bit-exact kernel.
__global__ __launch_bounds__(256) void ssm_y_kernel(const unsigned long long* __restrict__ spk,
                                                    const float* __restrict__ A,
                                                    const float* __restrict__ Bv,
                                                    const float* __restrict__ Cv,
                                                    const float* __restrict__ Dp,
                                                    float* __restrict__ y) {
  __shared__ float ws[JTAP];
  __shared__ float su[YTS + JTAP];

  const int tid = threadIdx.x;
  const int b   = blockIdx.y;
  const int t0  = blockIdx.x * YTS;
  const unsigned long long* __restrict__ sb = spk + (size_t)b * 16 * SEQ;

  if (tid < 64) {
    // wave 0: w_m = C . A^m . B via Krylov iteration
    const int lane = tid;
    float arow[64];
    #pragma unroll 8
    for (int s2 = 0; s2 < 64; ++s2) arow[s2] = A[lane * 64 + s2];
    float p = Bv[lane];
    const float cv = Cv[lane];
    for (int m = 0; m < JTAP; ++m) {
      float t = cv * p;
      #pragma unroll
      for (int off = 32; off; off >>= 1) t += __shfl_xor(t, off);
      if (lane == 0) ws[m] = t;
      float n0 = 0.f, n1 = 0.f, n2 = 0.f, n3 = 0.f;
      #pragma unroll
      for (int s2 = 0; s2 < 64; s2 += 4) {
        n0 = fmaf(arow[s2 + 0], __shfl(p, s2 + 0), n0);
        n1 = fmaf(arow[s2 + 1], __shfl(p, s2 + 1), n1);
        n2 = fmaf(arow[s2 + 2], __shfl(p, s2 + 2), n2);
        n3 = fmaf(arow[s2 + 3], __shfl(p, s2 + 3), n3);
      }
      p = (n0 + n1) + (n2 + n3);
    }
  } else {
    // waves 1-3: popcount u for t0-16 .. t0+YTS, overlapped with Krylov
    const int i = tid - 64;                 // 0..191
    for (int j = i; j < YTS + JTAP; j += 192) {
      const int t = t0 - JTAP + j;
      int cc = 0;
      #pragma unroll
      for (int wv = 0; wv < 16; ++wv)
        cc += (t >= 0) ? __popcll(sb[(size_t)wv * SEQ + t]) : 0;
      su[j] = cc * (1.0f / 1024.0f);
    }
  }
  __syncthreads();

  {
    const int j = tid;                      // 0..255 == YTS
    float acc = Dp[0] * su[JTAP + j];
    #pragma unroll
    for (int m = 0; m < JTAP; ++m) acc = fmaf(ws[m], su[JTAP + j - m], acc);
    y[(size_t)b * SEQ + t0 + j] = acc;
  }
}

// Phase 3: pure stream-out. grid = (SEQ/TS3, B_SZ) = 2048 blocks (8/CU).
// One barrier, 2 KB LDS, no serial prologue: read masks + y, compose, nt-store.
__global__ __launch_bounds__(256) void out_kernel(const unsigned long long* __restrict__ spk,
                                                  const float* __restrict__ y,
                                                  vfloat4* __restrict__ out) {
  __shared__ unsigned long long lm[16][TS3 + 1];   // +1 u64 pad: avoid 4-way bank alias
  __shared__ float sy[TS3];

  const int tid = threadIdx.x;
  const int b   = blockIdx.y;
  const int t0  = blockIdx.x * TS3;
  const unsigned long long* __restrict__ sb = spk + (size_t)b * 16 * SEQ;

  lm[tid >> 4][tid & 15] = sb[(size_t)(tid >> 4) * SEQ + t0 + (tid & 15)];
  if (tid < TS3) sy[tid] = y[(size_t)b * SEQ + t0 + tid];
  __syncthreads();

  const int wv = tid >> 4;
  const int sh = (tid & 15) * 4;
  vfloat4* op = out + (size_t)(b * SEQ + t0) * 256 + tid;
  #pragma unroll
  for (int j = 0; j < TS3; ++j) {
    const unsigned long long m = lm[wv][j];
    const float yv = sy[j];
    vfloat4 o;
    o.x = ((m >> (sh + 0)) & 1ull) ? 1.0f + yv : yv;
    o.y = ((m >> (sh + 1)) & 1ull) ? 1.0f + yv : yv;
    o.z = ((m >> (sh + 2)) & 1ull) ? 1.0f + yv : yv;
    o.w = ((m >> (sh + 3)) & 1ull) ? 1.0f + yv : yv;
    __builtin_nontemporal_store(o, &op[(size_t)j * 256]);
  }
}

extern "C" void kernel_launch(void* const* d_in, const int* in_sizes, int n_in,
                              void* d_out, int out_size, void* d_ws, size_t ws_size,
                              hipStream_t stream) {
  const float* x  = (const float*)d_in[0];   // (8, 4096, 1024)
  const float* A  = (const float*)d_in[1];   // (64, 64)
  const float* Bv = (const float*)d_in[2];   // (64, 1)
  const float* Cv = (const float*)d_in[3];   // (1, 64)
  const float* Dp = (const float*)d_in[4];   // (1, 1)

  unsigned long long* spk = (unsigned long long*)d_ws;                 // 4 MB
  float* yv = (float*)((char*)d_ws + ((size_t)B_SZ * 16 * SEQ * 8));   // 128 KB

  dim3 g1(HID / 256, B_SZ, NCH);
  snn_kernel<<<g1, 256, 0, stream>>>(x, spk);

  dim3 g2(SEQ / YTS, B_SZ);
  ssm_y_kernel<<<g2, 256, 0, stream>>>(spk, A, Bv, Cv, Dp, yv);

  dim3 g3(SEQ / TS3, B_SZ);
  out_kernel<<<g3, 256, 0, stream>>>(spk, yv, (vfloat4*)d_out);
}

// Round 2
// 284.071 us; speedup vs baseline: 1.0105x; 1.0105x over previous
//
#include <hip/hip_runtime.h>
#include <cstdint>
#include <cstddef>

#define B_SZ   8
#define SEQ    4096
#define HID    1024
#define NCH    8         // snn time chunks (reverted: 16 inflated warm-up reads for no net gain)
#define CHUNK  512       // SEQ / NCH
#define WARM   256       // warm-up steps; 0.9^256 contraction + spike-reset collapse => bit-exact
#define JTAP   16        // truncated SSM impulse-response taps
#define TS3    16        // out_kernel t-tile (2048 blocks, 8/CU)
#define YTS    256       // ssm_y t-tile (128 blocks)

typedef float vfloat4 __attribute__((ext_vector_type(4)));

// ws layout: u64 spk[B_SZ*16*SEQ] = 4 MB at offset 0
//            float y[B_SZ*SEQ]    = 128 KB at offset 4 MB
__device__ __forceinline__ void snn_step(float& v, float& r, float xv, bool& s) {
  // match reference rounding: separate mul + add (no FMA contraction)
  v = __fadd_rn(__fmul_rn(v, 0.9f), xv);
  s = (r <= 0.0f) && (v >= 1.0f);
  v = s ? 0.0f : v;
  r = s ? 5.0f : fmaxf(r - 1.0f, 0.0f);
}

__device__ __forceinline__ void proc32_emit(const float* xv, float& v, float& r, int lane,
                                            unsigned long long* __restrict__ sp, int t) {
  unsigned long long my = 0;
  #pragma unroll
  for (int k = 0; k < 32; ++k) {
    bool s; snn_step(v, r, xv[k], s);
    unsigned long long m = __ballot(s);
    my = ((lane & 31) == k) ? m : my;
  }
  if (lane < 32) sp[t + lane] = my;     // 256B coalesced burst per 32 steps
}

__device__ __forceinline__ void proc32_warm(const float* xv, float& v, float& r) {
  #pragma unroll
  for (int k = 0; k < 32; ++k) { bool s; snn_step(v, r, xv[k], s); }
}

// Phase 1: LIF scan, chunked in time with bit-exact warm-up restart.
// grid = (HID/256, B_SZ, NCH) = 256 blocks (1/CU), block = 256.
// Issued reads: (512 + 7*768)*8192 cols * 4B = 193 MB; warm re-reads are L2/L3-hot
// (chunk c's warm range is chunk c-1's concurrently-read emit range).
__global__ __launch_bounds__(256) void snn_kernel(const float* __restrict__ x,
                                                  unsigned long long* __restrict__ spk) {
  const int hid  = blockIdx.x * 256 + threadIdx.x;
  const int b    = blockIdx.y;
  const int c    = blockIdx.z;
  const int lane = threadIdx.x & 63;
  const int wv   = hid >> 6;                 // global hid-wave index 0..15
  const int t0   = c * CHUNK;
  const int t1   = t0 + CHUNK;
  const int tw   = (t0 >= WARM) ? (t0 - WARM) : 0;  // len in {512, 768}, %64==0
  const float* __restrict__ xp = x + (size_t)(b * SEQ) * HID + hid;
  unsigned long long* __restrict__ sp = spk + (size_t)(b * 16 + wv) * SEQ;

  float v = 0.0f, r = 0.0f;
  float xa[32], xb[32];

  #pragma unroll
  for (int k = 0; k < 32; ++k) xa[k] = xp[(size_t)(tw + k) * HID];

  for (int t = tw; t < t1; t += 64) {
    // prefetch batch B while processing A
    #pragma unroll
    for (int k = 0; k < 32; ++k) xb[k] = xp[(size_t)(t + 32 + k) * HID];

    if (t >= t0) proc32_emit(xa, v, r, lane, sp, t);
    else         proc32_warm(xa, v, r);

    // prefetch next batch A while processing B
    if (t + 64 < t1) {
      #pragma unroll
      for (int k = 0; k < 32; ++k) xa[k] = xp[(size_t)(t + 64 + k) * HID];
    }

    if (t + 32 >= t0) proc32_emit(xb, v, r, lane, sp, t + 32);
    else              proc32_warm(xb, v, r);
  }
}

// Phase 2: taps (Krylov, wave0) + popcount u + 16-tap conv -> y[b][t] (128 KB).
// grid = (SEQ/YTS, B_SZ) = 128 blocks. u math is integer (order-free, exact),
// tap + conv chains are verbatim from the bit-exact kernel.
__global__ __launch_bounds__(256) void ssm_y_kernel(const unsigned long long* __restrict__ spk,
                                                    const float* __restrict__ A,
                                                    const float* __restrict__ Bv,
                                                    const float* __restrict__ Cv,
                                                    const float* __restrict__ Dp,
                                                    float* __restrict__ y) {
  __shared__ float ws[JTAP];
  __shared__ float su[YTS + JTAP];

  const int tid = threadIdx.x;
  const int b   = blockIdx.y;
  const int t0  = blockIdx.x * YTS;
  const unsigned long long* __restrict__ sb = spk + (size_t)b * 16 * SEQ;

  if (tid < 64) {
    // wave 0: w_m = C . A^m . B via Krylov iteration
    const int lane = tid;
    float arow[64];
    #pragma unroll 8
    for (int s2 = 0; s2 < 64; ++s2) arow[s2] = A[lane * 64 + s2];
    float p = Bv[lane];
    const float cv = Cv[lane];
    for (int m = 0; m < JTAP; ++m) {
      float t = cv * p;
      #pragma unroll
      for (int off = 32; off; off >>= 1) t += __shfl_xor(t, off);
      if (lane == 0) ws[m] = t;
      float n0 = 0.f, n1 = 0.f, n2 = 0.f, n3 = 0.f;
      #pragma unroll
      for (int s2 = 0; s2 < 64; s2 += 4) {
        n0 = fmaf(arow[s2 + 0], __shfl(p, s2 + 0), n0);
        n1 = fmaf(arow[s2 + 1], __shfl(p, s2 + 1), n1);
        n2 = fmaf(arow[s2 + 2], __shfl(p, s2 + 2), n2);
        n3 = fmaf(arow[s2 + 3], __shfl(p, s2 + 3), n3);
      }
      p = (n0 + n1) + (n2 + n3);
    }
  } else {
    // waves 1-3: popcount u for t0-16 .. t0+YTS, overlapped with Krylov
    const int i = tid - 64;                 // 0..191
    for (int j = i; j < YTS + JTAP; j += 192) {
      const int t = t0 - JTAP + j;
      int cc = 0;
      #pragma unroll
      for (int wv = 0; wv < 16; ++wv)
        cc += (t >= 0) ? __popcll(sb[(size_t)wv * SEQ + t]) : 0;
      su[j] = cc * (1.0f / 1024.0f);
    }
  }
  __syncthreads();

  {
    const int j = tid;                      // 0..255 == YTS
    float acc = Dp[0] * su[JTAP + j];
    #pragma unroll
    for (int m = 0; m < JTAP; ++m) acc = fmaf(ws[m], su[JTAP + j - m], acc);
    y[(size_t)b * SEQ + t0 + j] = acc;
  }
}

// Phase 3: pure stream-out. grid = (SEQ/TS3, B_SZ) = 2048 blocks (8/CU).
// PLAIN stores (was nontemporal): nt bypasses TCC write-combining, capping the
// 134 MB stream at ~1.7-1.9 TB/s (vs 6.7 TB/s for the harness fill). Let L2
// combine the 16 B/lane stores into full HBM bursts.
__global__ __launch_bounds__(256) void out_kernel(const unsigned long long* __restrict__ spk,
                                                  const float* __restrict__ y,
                                                  vfloat4* __restrict__ out) {
  __shared__ unsigned long long lm[16][TS3 + 1];   // +1 u64 pad: avoid bank alias
  __shared__ float sy[TS3];

  const int tid = threadIdx.x;
  const int b   = blockIdx.y;
  const int t0  = blockIdx.x * TS3;
  const unsigned long long* __restrict__ sb = spk + (size_t)b * 16 * SEQ;

  lm[tid >> 4][tid & 15] = sb[(size_t)(tid >> 4) * SEQ + t0 + (tid & 15)];
  if (tid < TS3) sy[tid] = y[(size_t)b * SEQ + t0 + tid];
  __syncthreads();

  const int wv = tid >> 4;
  const int sh = (tid & 15) * 4;
  vfloat4* op = out + (size_t)(b * SEQ + t0) * 256 + tid;
  #pragma unroll
  for (int j = 0; j < TS3; ++j) {
    const unsigned long long m = lm[wv][j];
    const float yv = sy[j];
    vfloat4 o;
    o.x = ((m >> (sh + 0)) & 1ull) ? 1.0f + yv : yv;
    o.y = ((m >> (sh + 1)) & 1ull) ? 1.0f + yv : yv;
    o.z = ((m >> (sh + 2)) & 1ull) ? 1.0f + yv : yv;
    o.w = ((m >> (sh + 3)) & 1ull) ? 1.0f + yv : yv;
    op[(size_t)j * 256] = o;
  }
}

extern "C" void kernel_launch(void* const* d_in, const int* in_sizes, int n_in,
                              void* d_out, int out_size, void* d_ws, size_t ws_size,
                              hipStream_t stream) {
  const float* x  = (const float*)d_in[0];   // (8, 4096, 1024)
  const float* A  = (const float*)d_in[1];   // (64, 64)
  const float* Bv = (const float*)d_in[2];   // (64, 1)
  const float* Cv = (const float*)d_in[3];   // (1, 64)
  const float* Dp = (const float*)d_in[4];   // (1, 1)

  unsigned long long* spk = (unsigned long long*)d_ws;                 // 4 MB
  float* yv = (float*)((char*)d_ws + ((size_t)B_SZ * 16 * SEQ * 8));   // 128 KB

  dim3 g1(HID / 256, B_SZ, NCH);
  snn_kernel<<<g1, 256, 0, stream>>>(x, spk);

  dim3 g2(SEQ / YTS, B_SZ);
  ssm_y_kernel<<<g2, 256, 0, stream>>>(spk, A, Bv, Cv, Dp, yv);

  dim3 g3(SEQ / TS3, B_SZ);
  out_kernel<<<g3, 256, 0, stream>>>(spk, yv, (vfloat4*)d_out);
}